// Round 2
// baseline (191.902 us; speedup 1.0000x reference)
//
#include <hip/hip_runtime.h>
#include <hip/hip_bf16.h>
#include <cstdint>
#include <cstddef>

// Problem constants: B=4, S=4096, D=1024, E=10, R=4, TOPK=2, SCALING=1/R=0.25
#define M_TOT 16384
#define D_DIM 1024
#define E_NUM 10
#define R_RANK 4

typedef __attribute__((ext_vector_type(8))) short bf16x8;
typedef __attribute__((ext_vector_type(4))) float f32x4;
typedef unsigned short u16;
typedef unsigned int u32;

__device__ __forceinline__ u16 f2bf(float f) {
  union { float f; u32 u; } v; v.f = f;
  u32 r = v.u + 0x7fffu + ((v.u >> 16) & 1u);   // RNE
  return (u16)(r >> 16);
}
__device__ __forceinline__ float bf2f(u16 u) {
  union { u32 u; float f; } v; v.u = ((u32)u) << 16; return v.f;
}

// ---------------- W_base fp32 -> bf16 ----------------
__global__ void conv_w(const float* __restrict__ W, u16* __restrict__ Wb) {
  const int i = (blockIdx.x * 256 + threadIdx.x) * 8;
  float4 a = *(const float4*)(W + i);
  float4 b = *(const float4*)(W + i + 4);
  *(ushort4*)(Wb + i)     = make_ushort4(f2bf(a.x), f2bf(a.y), f2bf(a.z), f2bf(a.w));
  *(ushort4*)(Wb + i + 4) = make_ushort4(f2bf(b.x), f2bf(b.y), f2bf(b.z), f2bf(b.w));
}

// ---------------- gating + LoRA-down prep ----------------
// grid 256 blocks x 1024 threads; 64 tokens/block (16 waves x 4 tokens).
// Logits in fp32 (selection must match np fp32 reference); h with bf16 lora_down.
__global__ __launch_bounds__(1024)
void moe_prep(const float* __restrict__ x, const float* __restrict__ gW,
              const float* __restrict__ gb, const float* __restrict__ ld,
              int* __restrict__ ids, float* __restrict__ cvals) {
  __shared__ float sgW[E_NUM * D_DIM];            // 40 KB fp32
  __shared__ u16   sld[E_NUM * R_RANK * D_DIM];   // 80 KB bf16
  __shared__ float sgb[16];
  const int tid = threadIdx.x;
  for (int i = tid; i < E_NUM * D_DIM; i += 1024) sgW[i] = gW[i];
  for (int i = tid; i < E_NUM * R_RANK * D_DIM; i += 1024) sld[i] = f2bf(ld[i]);
  if (tid < E_NUM) sgb[tid] = gb[tid];
  __syncthreads();

  const int lane = tid & 63, w = tid >> 6;
#pragma unroll 1
  for (int it = 0; it < 4; ++it) {
    const int t = blockIdx.x * 64 + w * 4 + it;
    float4 xv[4];
#pragma unroll
    for (int j = 0; j < 4; ++j)
      xv[j] = *(const float4*)(x + (size_t)t * D_DIM + j * 256 + lane * 4);

    float lg[E_NUM];
#pragma unroll
    for (int e = 0; e < E_NUM; ++e) {
      float s = 0.f;
#pragma unroll
      for (int j = 0; j < 4; ++j) {
        float4 wv = *(const float4*)(sgW + e * D_DIM + j * 256 + lane * 4);
        s += xv[j].x * wv.x + xv[j].y * wv.y + xv[j].z * wv.z + xv[j].w * wv.w;
      }
#pragma unroll
      for (int o = 32; o; o >>= 1) s += __shfl_xor(s, o);
      lg[e] = s + sgb[e];
    }
    // top-2 (ties -> lower index, matching jax.lax.top_k)
    int e0 = 0; float v0 = lg[0];
#pragma unroll
    for (int e = 1; e < E_NUM; ++e) if (lg[e] > v0) { v0 = lg[e]; e0 = e; }
    int e1 = -1; float v1 = -3.0e38f;
#pragma unroll
    for (int e = 0; e < E_NUM; ++e) if (e != e0 && lg[e] > v1) { v1 = lg[e]; e1 = e; }
    const float pp = expf(v1 - v0);
    const float inv = 1.f / (1.f + pp);
    const float w0 = inv, w1 = pp * inv;

    float hv[8];
#pragma unroll
    for (int qq = 0; qq < 8; ++qq) {
      const int row = (qq < 4) ? (e0 * 4 + qq) : (e1 * 4 + (qq - 4));
      float s = 0.f;
#pragma unroll
      for (int j = 0; j < 4; ++j) {
        ushort4 uv = *(const ushort4*)(sld + row * D_DIM + j * 256 + lane * 4);
        s += xv[j].x * bf2f(uv.x) + xv[j].y * bf2f(uv.y) +
             xv[j].z * bf2f(uv.z) + xv[j].w * bf2f(uv.w);
      }
#pragma unroll
      for (int o = 32; o; o >>= 1) s += __shfl_xor(s, o);
      hv[qq] = s;
    }
    if (lane == 0) {
      ids[t * 2] = e0; ids[t * 2 + 1] = e1;
      const float s0 = w0 * 0.25f, s1 = w1 * 0.25f;  // fold softmax weight * SCALING
      *(float4*)(cvals + t * 8)     = make_float4(hv[0]*s0, hv[1]*s0, hv[2]*s0, hv[3]*s0);
      *(float4*)(cvals + t * 8 + 4) = make_float4(hv[4]*s1, hv[5]*s1, hv[6]*s1, hv[7]*s1);
    }
  }
}

// ---------------- main GEMM: out = x @ W^T + bias + sparse-LoRA epilogue ----
// 128x128 tile, BK=64, 4 waves (2x2), mfma 16x16x32 bf16.
// B staged via global_load_lds (XOR swizzle via permuted global chunk index),
// A reg-staged fp32->bf16 with swizzled ds_write + next-tile prefetch.
__global__ __launch_bounds__(256, 2)
void moe_gemm(const float* __restrict__ x, const u16* __restrict__ Wb,
              const float* __restrict__ bias, const int* __restrict__ ids,
              const float* __restrict__ cvals, const float* __restrict__ lup,
              float* __restrict__ out) {
  __shared__ u16 Al[128 * 64];   // 16 KB, [row][k] bf16, XOR-swizzled
  __shared__ u16 Bl[128 * 64];   // 16 KB

  const int tid = threadIdx.x;
  const int lane = tid & 63;
  const int wid = tid >> 6;
  const int wm = wid >> 1, wn = wid & 1;

  // XCD-aware mapping: all 8 col-blocks of one row-panel on the same XCD
  const int p = blockIdx.x;
  const int cx = p & 7, q = p >> 3;
  const int nb = q & 7, mb = cx * 16 + (q >> 3);
  const int m0 = mb * 128, n0 = nb * 128;

  f32x4 acc[4][4] = {};

  float4 av[8];
#pragma unroll
  for (int t = 0; t < 8; ++t) {                       // preload A tile kt=0
    int c = t * 256 + tid;
    int row = c >> 4, k4 = c & 15;
    av[t] = *(const float4*)(x + (size_t)(m0 + row) * D_DIM + k4 * 4);
  }

#pragma unroll 1
  for (int kt = 0; kt < 16; ++kt) {
    const int k0 = kt * 64;
    // ---- B tile: async global->LDS, 16B/lane; source chunk index XORed so the
    //      linear LDS write lands in swizzled layout.
#pragma unroll
    for (int i = 0; i < 4; ++i) {
      int c = i * 256 + tid;                           // wave-contiguous
      int row = c >> 3;
      int kc = (c & 7) ^ (row & 7);
      const u16* g = Wb + (size_t)(n0 + row) * D_DIM + k0 + kc * 8;
      __builtin_amdgcn_global_load_lds(
          (const __attribute__((address_space(1))) u32*)g,
          (__attribute__((address_space(3))) u32*)&Bl[c * 8], 16, 0, 0);
    }
    // ---- A tile: convert + swizzled ds_write_b64
#pragma unroll
    for (int t = 0; t < 8; ++t) {
      int c = t * 256 + tid;
      int row = c >> 4, k4 = c & 15;
      int off = (row * 128 + k4 * 8) ^ ((row & 7) << 4);
      ushort4 u = make_ushort4(f2bf(av[t].x), f2bf(av[t].y), f2bf(av[t].z), f2bf(av[t].w));
      *(ushort4*)((char*)Al + off) = u;
    }
    __syncthreads();
    // prefetch next A tile under the MFMA phase (T14)
    if (kt < 15) {
#pragma unroll
      for (int t = 0; t < 8; ++t) {
        int c = t * 256 + tid;
        int row = c >> 4, k4 = c & 15;
        av[t] = *(const float4*)(x + (size_t)(m0 + row) * D_DIM + (k0 + 64) + k4 * 4);
      }
    }
    // ---- compute: 2 x (8 ds_read_b128 + 16 MFMA)
#pragma unroll
    for (int kk = 0; kk < 2; ++kk) {
      bf16x8 af[4], bfr[4];
      const int kb = (kk * 32 + ((lane >> 4) * 8)) * 2;
#pragma unroll
      for (int m = 0; m < 4; ++m) {
        int row = wm * 64 + m * 16 + (lane & 15);
        int off = (row * 128 + kb) ^ ((row & 7) << 4);
        af[m] = *(const bf16x8*)((const char*)Al + off);
      }
#pragma unroll
      for (int n = 0; n < 4; ++n) {
        int row = wn * 64 + n * 16 + (lane & 15);
        int off = (row * 128 + kb) ^ ((row & 7) << 4);
        bfr[n] = *(const bf16x8*)((const char*)Bl + off);
      }
#pragma unroll
      for (int m = 0; m < 4; ++m)
#pragma unroll
        for (int n = 0; n < 4; ++n)
          acc[m][n] = __builtin_amdgcn_mfma_f32_16x16x32_bf16(af[m], bfr[n], acc[m][n], 0, 0, 0);
    }
    __syncthreads();
  }

  // ---- epilogue: bias + sparse LoRA, fp32 store
  const int rg = lane >> 4, cl = lane & 15;
  const int baser = m0 + wm * 64, basec = n0 + wn * 64;
  float bs[4];
#pragma unroll
  for (int n = 0; n < 4; ++n) bs[n] = bias[basec + n * 16 + cl];
#pragma unroll
  for (int m = 0; m < 4; ++m) {
#pragma unroll
    for (int j = 0; j < 4; ++j) {
      const int rr = baser + m * 16 + rg * 4 + j;    // C/D row = (lane>>4)*4 + j
      const int2 id2 = *(const int2*)(ids + rr * 2);
      const float4 c0 = *(const float4*)(cvals + rr * 8);
      const float4 c1 = *(const float4*)(cvals + rr * 8 + 4);
      const float* u0b = lup + (size_t)id2.x * (D_DIM * R_RANK);
      const float* u1b = lup + (size_t)id2.y * (D_DIM * R_RANK);
#pragma unroll
      for (int n = 0; n < 4; ++n) {
        const int cc = basec + n * 16 + cl;          // C/D col = lane&15
        float4 u0 = *(const float4*)(u0b + cc * 4);
        float4 u1 = *(const float4*)(u1b + cc * 4);
        float v = acc[m][n][j] + bs[n];
        v += c0.x * u0.x + c0.y * u0.y + c0.z * u0.z + c0.w * u0.w;
        v += c1.x * u1.x + c1.y * u1.y + c1.z * u1.z + c1.w * u1.w;
        out[(size_t)rr * D_DIM + cc] = v;
      }
    }
  }
}

extern "C" void kernel_launch(void* const* d_in, const int* in_sizes, int n_in,
                              void* d_out, int out_size, void* d_ws, size_t ws_size,
                              hipStream_t stream) {
  const float* x   = (const float*)d_in[0];   // [16384,1024]
  const float* Wb_ = (const float*)d_in[1];   // [1024,1024]  (o,d)
  const float* bb  = (const float*)d_in[2];   // [1024]
  const float* gW  = (const float*)d_in[3];   // [10,1024]
  const float* gb  = (const float*)d_in[4];   // [10]
  const float* ld  = (const float*)d_in[5];   // [10,4,1024]
  const float* lup = (const float*)d_in[6];   // [10,1024,4]

  // ws layout: [0, 2MB) W bf16 | [2MB, +128KB) ids | [.., +512KB) cvals  (~2.65MB)
  u16*   Wbf   = (u16*)d_ws;
  int*   ids   = (int*)((char*)d_ws + (2u << 20));
  float* cvals = (float*)((char*)d_ws + (2u << 20) + (128u << 10));

  hipLaunchKernelGGL(conv_w,   dim3(512),  dim3(256),  0, stream, Wb_, Wbf);
  hipLaunchKernelGGL(moe_prep, dim3(256),  dim3(1024), 0, stream, x, gW, gb, ld, ids, cvals);
  hipLaunchKernelGGL(moe_gemm, dim3(1024), dim3(256),  0, stream, x, Wbf, bb, ids, cvals, lup,
                     (float*)d_out);
}